// Round 13
// baseline (13.410 us; speedup 1.0000x reference)
//
#include <hip/hip_runtime.h>
#include <math.h>

#define B 4
#define S 4096
#define N 4096
#define BLK 1024           // 16 waves, 1 block/CU, 4 waves/SIMD
#define NW 16
#define W 2                // two 32-col B-frags -> 64 s per block
#define PASS 2048          // cloud pts per LDS pass per cloud (32 KB x 2 clouds)
#define NPASS 2
#define JTW 4              // j-tiles (32 rows) per wave per pass = PASS/32/NW
#define INF 3.4e38f

typedef _Float16 f16x8  __attribute__((ext_vector_type(8)));
typedef float    f32x16 __attribute__((ext_vector_type(16)));

// 32x32x16 K-packed Gram MFMA, full-N per block (verified in R12).
// A (cloud pt j): {-y0,-y1,-y2, hy_hi, hy_lo, 0,0,0}
// B (grid s, cols=lane&31): lanes<32 {x0,x1,x2,1,1,0,0,0}; lanes>=32 zero
// (kills A's k=8..15). D[j][s] = hy - x.y ; u = hx + min_j D.
// Staging: threads 0-511 stage preds, 512-1023 stage gts; 4 pts/thread via
// 3 coalesced float4 loads; pass p+1 loads issued BEFORE compute of pass p.
__global__ __launch_bounds__(BLK) void sdf_mfma(
    const float* __restrict__ grid,   // [B,S,3]
    const float* __restrict__ gts,    // [B,N,3]
    const float* __restrict__ preds,  // [B,N,3]
    float* __restrict__ pb)           // [B][S/64]
{
    __shared__ float4 Ap[PASS];       // 32 KB
    __shared__ float4 Ag[PASS];       // 32 KB

    const int tid   = threadIdx.x;
    const int lane  = tid & 63;
    const int wv    = tid >> 6;       // 0..15
    const int l31   = lane & 31;
    const int stile = blockIdx.x;     // 64 tiles of 64 s
    const int b     = blockIdx.y;
    const int scol  = stile * 64;

    // ---- B-frags + hx ----
    const bool lo32 = (lane < 32);
    f16x8 bf[W];
    float hx[W];
    #pragma unroll
    for (int w = 0; w < W; ++w) {
        const float* xp = grid + ((size_t)b * S + scol + w * 32 + l31) * 3;
        float x0 = (float)(_Float16)xp[0];
        float x1 = (float)(_Float16)xp[1];
        float x2 = (float)(_Float16)xp[2];
        hx[w] = 0.5f * (x0 * x0 + x1 * x1 + x2 * x2);
        f16x8 bb = { (_Float16)x0, (_Float16)x1, (_Float16)x2,
                     (_Float16)1.f, (_Float16)1.f,
                     (_Float16)0.f, (_Float16)0.f, (_Float16)0.f };
        f16x8 z  = { (_Float16)0.f, (_Float16)0.f, (_Float16)0.f, (_Float16)0.f,
                     (_Float16)0.f, (_Float16)0.f, (_Float16)0.f, (_Float16)0.f };
        bf[w] = lo32 ? bb : z;
    }

    // ---- staging role: wave-uniform split (waves 0-7 preds, 8-15 gts) ----
    const bool doP  = (tid < BLK / 2);
    const int  st   = tid & (BLK / 2 - 1);        // 0..511, pts [4st,4st+4)
    const float* cbase = (doP ? preds : gts) + (size_t)b * N * 3;
    const float4* csrc = (const float4*)cbase;    // 1536 float4 per pass
    float4* Abuf = doP ? Ap : Ag;

    float4 r0, r1, r2;
    // load pass 0
    {
        const float4* v = csrc + 3 * st;
        r0 = v[0]; r1 = v[1]; r2 = v[2];
    }
    // pack pass 0
    {
        const float ys[4][3] = { { r0.x, r0.y, r0.z }, { r0.w, r1.x, r1.y },
                                 { r1.z, r1.w, r2.x }, { r2.y, r2.z, r2.w } };
        #pragma unroll
        for (int k = 0; k < 4; ++k) {
            float y0 = (float)(_Float16)ys[k][0];
            float y1 = (float)(_Float16)ys[k][1];
            float y2 = (float)(_Float16)ys[k][2];
            float hy = 0.5f * (y0 * y0 + y1 * y1 + y2 * y2);
            _Float16 hh = (_Float16)hy;
            _Float16 hl = (_Float16)(hy - (float)hh);
            f16x8 a = { (_Float16)(-y0), (_Float16)(-y1), (_Float16)(-y2),
                        hh, hl, (_Float16)0.f, (_Float16)0.f, (_Float16)0.f };
            *(f16x8*)&Abuf[4 * st + k] = a;
        }
    }
    __syncthreads();

    float accp[W], accg[W];
    #pragma unroll
    for (int w = 0; w < W; ++w) { accp[w] = INF; accg[w] = INF; }

    const f32x16 zc = { 0.f, 0.f, 0.f, 0.f, 0.f, 0.f, 0.f, 0.f,
                        0.f, 0.f, 0.f, 0.f, 0.f, 0.f, 0.f, 0.f };

    #pragma unroll
    for (int p = 0; p < NPASS; ++p) {
        // prefetch next pass into registers (latency hides under compute)
        if (p + 1 < NPASS) {
            const float4* v = csrc + (size_t)(p + 1) * (PASS * 3 / 4) + 3 * st;
            r0 = v[0]; r1 = v[1]; r2 = v[2];
        }

        // ---- compute: wave's JTW j-tiles of 32 rows each ----
        const char* app = (const char*)Ap + ((size_t)wv * JTW * 32 + l31) * 16;
        const char* agp = (const char*)Ag + ((size_t)wv * JTW * 32 + l31) * 16;
        #pragma unroll
        for (int jt = 0; jt < JTW; ++jt) {
            const f16x8 afp = *(const f16x8*)(app + jt * 512);
            const f16x8 afg = *(const f16x8*)(agp + jt * 512);
            #pragma unroll
            for (int w = 0; w < W; ++w) {
                f32x16 d = __builtin_amdgcn_mfma_f32_32x32x16_f16(afp, bf[w], zc, 0, 0, 0);
                float a = accp[w];
                a = fminf(fminf(a, d[0]),  d[1]);
                a = fminf(fminf(a, d[2]),  d[3]);
                a = fminf(fminf(a, d[4]),  d[5]);
                a = fminf(fminf(a, d[6]),  d[7]);
                a = fminf(fminf(a, d[8]),  d[9]);
                a = fminf(fminf(a, d[10]), d[11]);
                a = fminf(fminf(a, d[12]), d[13]);
                a = fminf(fminf(a, d[14]), d[15]);
                accp[w] = a;
            }
            #pragma unroll
            for (int w = 0; w < W; ++w) {
                f32x16 d = __builtin_amdgcn_mfma_f32_32x32x16_f16(afg, bf[w], zc, 0, 0, 0);
                float a = accg[w];
                a = fminf(fminf(a, d[0]),  d[1]);
                a = fminf(fminf(a, d[2]),  d[3]);
                a = fminf(fminf(a, d[4]),  d[5]);
                a = fminf(fminf(a, d[6]),  d[7]);
                a = fminf(fminf(a, d[8]),  d[9]);
                a = fminf(fminf(a, d[10]), d[11]);
                a = fminf(fminf(a, d[12]), d[13]);
                a = fminf(fminf(a, d[14]), d[15]);
                accg[w] = a;
            }
        }
        __syncthreads();   // all waves done reading before overwrite / reuse

        if (p + 1 < NPASS) {
            const float ys[4][3] = { { r0.x, r0.y, r0.z }, { r0.w, r1.x, r1.y },
                                     { r1.z, r1.w, r2.x }, { r2.y, r2.z, r2.w } };
            #pragma unroll
            for (int k = 0; k < 4; ++k) {
                float y0 = (float)(_Float16)ys[k][0];
                float y1 = (float)(_Float16)ys[k][1];
                float y2 = (float)(_Float16)ys[k][2];
                float hy = 0.5f * (y0 * y0 + y1 * y1 + y2 * y2);
                _Float16 hh = (_Float16)hy;
                _Float16 hl = (_Float16)(hy - (float)hh);
                f16x8 a = { (_Float16)(-y0), (_Float16)(-y1), (_Float16)(-y2),
                            hh, hl, (_Float16)0.f, (_Float16)0.f, (_Float16)0.f };
                *(f16x8*)&Abuf[4 * st + k] = a;
            }
            __syncthreads();
        }
    }

    // ---- cross-lane + cross-wave + block tail (as R12) ----
    float* sm = (float*)Ap;   // reuse LDS: [NW][2][64] (barrier above)
    #pragma unroll
    for (int w = 0; w < W; ++w) {
        float mp = fminf(accp[w], __shfl_xor(accp[w], 32, 64));
        float mg = fminf(accg[w], __shfl_xor(accg[w], 32, 64));
        if (lo32) {
            sm[(wv * 2 + 0) * 64 + w * 32 + l31] = hx[w] + mp;
            sm[(wv * 2 + 1) * 64 + w * 32 + l31] = hx[w] + mg;
        }
    }
    __syncthreads();
    if (tid < 64) {
        float mp = INF, mg = INF;
        #pragma unroll
        for (int v = 0; v < NW; ++v) {
            mp = fminf(mp, sm[(v * 2 + 0) * 64 + tid]);
            mg = fminf(mg, sm[(v * 2 + 1) * 64 + tid]);
        }
        float v = fabsf(sqrtf(fmaxf(2.f * mp, 0.f)) - sqrtf(fmaxf(2.f * mg, 0.f)));
        #pragma unroll
        for (int off = 32; off > 0; off >>= 1)
            v += __shfl_down(v, off, 64);
        if (tid == 0) pb[b * 64 + stile] = v;
    }
}

// Final: 256 threads = 4 waves; wave b reduces its 64 tile-sums -> out[b].
__global__ __launch_bounds__(256) void sdf_final(
    const float* __restrict__ pb, float* __restrict__ out)
{
    const int tid = threadIdx.x;
    float v = pb[tid];
    #pragma unroll
    for (int off = 32; off > 0; off >>= 1)
        v += __shfl_down(v, off, 64);
    if ((tid & 63) == 0) out[tid >> 6] = v / (float)S;
}

extern "C" void kernel_launch(void* const* d_in, const int* in_sizes, int n_in,
                              void* d_out, int out_size, void* d_ws, size_t ws_size,
                              hipStream_t stream) {
    const float* grid  = (const float*)d_in[0];
    const float* gts   = (const float*)d_in[1];
    const float* preds = (const float*)d_in[2];
    float* out = (float*)d_out;
    float* pb  = (float*)d_ws;        // 256 floats

    dim3 g1(S / 64, B);               // (64, 4) = 256 blocks, 1 per CU
    sdf_mfma<<<g1, BLK, 0, stream>>>(grid, gts, preds, pb);

    sdf_final<<<1, 256, 0, stream>>>(pb, out);
}